// Round 1
// baseline (997.988 us; speedup 1.0000x reference)
//
#include <hip/hip_runtime.h>
#include <math.h>

#define D_DIM 128
#define H_DIM 256
#define W_DIM 256
#define NIMG 2
#define NPI (D_DIM * H_DIM * W_DIM)        // 8388608 per image
#define NTOT (NIMG * NPI)                  // 16777216 total

#define TD 8
#define TH 8
#define TW 32

#define NUM_ITER 20
#define STOP_THRESH 1e-4

__device__ __forceinline__ float leaky(float x) { return x >= 0.f ? x : 0.01f * x; }

__global__ void init_slots(double* slots) {
    int t = threadIdx.x;
    if (t < 32) slots[t] = 0.0;
}

// One fused step:
//   e   = minpool3(a_in)          (erosion; +inf SAME padding)
//   a_out = e                      (next iteration's input)
//   d   = maxpool3(e)              (dilation; -inf SAME padding)
//   delta = leaky(a_in - d)
//   step==0 : skel = delta
//   step>=1 : upd = leaky(delta - skel*delta); skel += upd; accumulate dn
__global__ __launch_bounds__(256) void skel_step(
    const float* __restrict__ a_in,
    float* __restrict__ a_out,
    float* __restrict__ skel,
    double* __restrict__ slots,
    int step)
{
    __shared__ float A[5184];   // 12*12*36 input tile (halo 2)
    __shared__ float B[4896];   // 12*12*34 scratch (minW / e / maxH)
    __shared__ float wsum[4];
    __shared__ int s_active;

    const int t = threadIdx.x;

    // --- gating: active iff all previous dn >= STOP_THRESH ---
    if (t == 0) {
        int act = 1;
        for (int j = 1; j < step; ++j) {
            double mean = slots[j] / (double)NTOT;
            if (!(mean >= STOP_THRESH)) { act = 0; break; }
        }
        s_active = act;
    }
    __syncthreads();
    if (!s_active) return;

    const int bx = blockIdx.x;            // W tile: 0..7
    const int by = blockIdx.y;            // H tile: 0..31
    const int bz = blockIdx.z & 15;       // D tile: 0..15
    const int img = blockIdx.z >> 4;      // image: 0..1
    const int z0 = bz * TD, y0 = by * TH, x0 = bx * TW;

    const float* in = a_in + (size_t)img * NPI;

    // --- stage 1: load input tile with halo 2, +inf outside volume ---
    for (int idx = t; idx < 12 * 12 * 36; idx += 256) {
        int d = idx / (12 * 36);
        int r = idx - d * (12 * 36);
        int h = r / 36;
        int w = r - h * 36;
        int gz = z0 - 2 + d, gy = y0 - 2 + h, gx = x0 - 2 + w;
        float v = INFINITY;
        if ((unsigned)gz < D_DIM && (unsigned)gy < H_DIM && (unsigned)gx < W_DIM)
            v = in[((size_t)gz * H_DIM + gy) * W_DIM + gx];
        A[idx] = v;
    }
    __syncthreads();

    // --- stage 2: stash center a values (one D-column per thread) ---
    const int oh = t >> 5, ow = t & 31;
    float ac[TD];
    #pragma unroll
    for (int i = 0; i < TD; ++i)
        ac[i] = A[((2 + i) * 12 + (2 + oh)) * 36 + (2 + ow)];

    // --- stage 3: min over W -> B[12][12][34] ---
    for (int idx = t; idx < 12 * 12 * 34; idx += 256) {
        int d = idx / (12 * 34);
        int r = idx - d * (12 * 34);
        int h = r / 34;
        int w = r - h * 34;
        int base = (d * 12 + h) * 36 + w;
        B[idx] = fminf(fminf(A[base], A[base + 1]), A[base + 2]);
    }
    __syncthreads();

    // --- stage 4: min over H -> A[12][10][34] ---
    for (int idx = t; idx < 12 * 10 * 34; idx += 256) {
        int d = idx / (10 * 34);
        int r = idx - d * (10 * 34);
        int h = r / 34;
        int w = r - h * 34;
        int base = (d * 12 + h) * 34 + w;
        A[idx] = fminf(fminf(B[base], B[base + 34]), B[base + 68]);
    }
    __syncthreads();

    // --- stage 5: min over D -> e = B[10][10][34]; mask out-of-volume to -inf ---
    for (int idx = t; idx < 10 * 10 * 34; idx += 256) {
        int d = idx / (10 * 34);
        int r = idx - d * (10 * 34);
        int h = r / 34;
        int w = r - h * 34;
        int base = (d * 10 + h) * 34 + w;
        float v = fminf(fminf(A[base], A[base + 340]), A[base + 680]);
        int gz = z0 - 1 + d, gy = y0 - 1 + h, gx = x0 - 1 + w;
        if (!((unsigned)gz < D_DIM && (unsigned)gy < H_DIM && (unsigned)gx < W_DIM))
            v = -INFINITY;
        B[idx] = v;
    }
    __syncthreads();

    // --- stage 6: write a_out = erosion (centers of e) ---
    if (step < NUM_ITER) {
        float* aout = a_out + (size_t)img * NPI;
        #pragma unroll
        for (int i = 0; i < TD; ++i) {
            float ev = B[((1 + i) * 10 + (1 + oh)) * 34 + (1 + ow)];
            aout[((size_t)(z0 + i) * H_DIM + (y0 + oh)) * W_DIM + (x0 + ow)] = ev;
        }
    }

    // --- stage 7: max over W -> A[10][10][32] ---
    for (int idx = t; idx < 10 * 10 * 32; idx += 256) {
        int d = idx / (10 * 32);
        int r = idx - d * (10 * 32);
        int h = r >> 5;
        int w = r & 31;
        int base = (d * 10 + h) * 34 + w;
        A[idx] = fmaxf(fmaxf(B[base], B[base + 1]), B[base + 2]);
    }
    __syncthreads();

    // --- stage 8: max over H -> B[10][8][32] ---
    for (int idx = t; idx < 10 * 8 * 32; idx += 256) {
        int d = idx / (8 * 32);
        int r = idx - d * (8 * 32);
        int h = r >> 5;
        int w = r & 31;
        int base = (d * 10 + h) * 32 + w;
        B[idx] = fmaxf(fmaxf(A[base], A[base + 32]), A[base + 64]);
    }
    __syncthreads();

    // --- stage 9: max over D + elementwise skel update ---
    float* sk = skel + (size_t)img * NPI;
    float lsum = 0.f;
    #pragma unroll
    for (int i = 0; i < TD; ++i) {
        int base = (i * 8 + oh) * 32 + ow;
        float dmax = fmaxf(fmaxf(B[base], B[base + 256]), B[base + 512]);
        float delta = leaky(ac[i] - dmax);
        size_t gi = ((size_t)(z0 + i) * H_DIM + (y0 + oh)) * W_DIM + (x0 + ow);
        if (step == 0) {
            sk[gi] = delta;
        } else {
            float g = sk[gi];
            float upd = leaky(delta - g * delta);
            float gnew = g + upd;
            sk[gi] = gnew;
            lsum += (step == 1) ? fabsf(gnew) : fabsf(upd);
        }
    }

    // --- reduction: dn accumulation ---
    if (step > 0) {
        #pragma unroll
        for (int off = 32; off > 0; off >>= 1)
            lsum += __shfl_down(lsum, off, 64);
        int lane = t & 63, wid = t >> 6;
        if (lane == 0) wsum[wid] = lsum;
        __syncthreads();
        if (t == 0) {
            float b = wsum[0] + wsum[1] + wsum[2] + wsum[3];
            atomicAdd(&slots[step], (double)b);
        }
    }
}

extern "C" void kernel_launch(void* const* d_in, const int* in_sizes, int n_in,
                              void* d_out, int out_size, void* d_ws, size_t ws_size,
                              hipStream_t stream) {
    const float* img = (const float*)d_in[0];
    float* out = (float*)d_out;
    float* buf0 = (float*)d_ws;
    float* buf1 = buf0 + NTOT;
    double* slots = (double*)(buf1 + NTOT);

    init_slots<<<1, 64, 0, stream>>>(slots);

    dim3 grid(W_DIM / TW, H_DIM / TH, (D_DIM / TD) * NIMG);
    for (int s = 0; s <= NUM_ITER; ++s) {
        const float* ain = (s == 0) ? img : ((s & 1) ? buf0 : buf1);
        float* aout = (s & 1) ? buf1 : buf0;
        skel_step<<<grid, 256, 0, stream>>>(ain, aout, out, slots, s);
    }
}

// Round 2
// 493.136 us; speedup vs baseline: 2.0238x; 2.0238x over previous
//
#include <hip/hip_runtime.h>
#include <math.h>

#define D_DIM 128
#define H_DIM 256
#define W_DIM 256
#define HW (H_DIM * W_DIM)
#define NIMG 2
#define NPI (D_DIM * HW)
#define NTOT (NIMG * NPI)

#define TDZ 32
#define TH 8
#define TW 32
#define FH 12      // TH+4 (halo 2)
#define FW 36      // TW+4
#define MH 10      // TH+2 (halo 1)
#define MW 34      // TW+2

#define NUM_ITER 20
#define STOP_THRESH 1e-4

__device__ __forceinline__ float leaky(float x) { return x >= 0.f ? x : 0.01f * x; }

__device__ __forceinline__ float min9(const float* s, int b) {
    float a = fminf(fminf(s[b], s[b + 1]), s[b + 2]);
    float c = fminf(fminf(s[b + FW], s[b + FW + 1]), s[b + FW + 2]);
    float d = fminf(fminf(s[b + 2 * FW], s[b + 2 * FW + 1]), s[b + 2 * FW + 2]);
    return fminf(fminf(a, c), d);
}

__device__ __forceinline__ float max9(const float* s, int b) {
    float a = fmaxf(fmaxf(s[b], s[b + 1]), s[b + 2]);
    float c = fmaxf(fmaxf(s[b + MW], s[b + MW + 1]), s[b + MW + 2]);
    float d = fmaxf(fmaxf(s[b + 2 * MW], s[b + 2 * MW + 1]), s[b + 2 * MW + 2]);
    return fmaxf(fmaxf(a, c), d);
}

__global__ void init_slots(double* slots) {
    if (threadIdx.x < 32) slots[threadIdx.x] = 0.0;
}

// Rolling-slice fused step:
//   e = minpool3^3(a_in) (erosion, +inf pad), a_out = e,
//   d = maxpool3^3(e)    (-inf pad == exclude out-of-volume),
//   delta = leaky(a_in - d); skel update + dn accumulation.
__global__ __launch_bounds__(256) void skel_step(
    const float* __restrict__ a_in,
    float* __restrict__ a_out,
    float* __restrict__ skel,
    double* __restrict__ slots,
    int step)
{
    __shared__ float aS[FH * FW];        // 432: input slice footprint (halo 2)
    __shared__ float mHW[3][MH * MW];    // 1020: min over W,H, 3-slice circular
    __shared__ float eT[MH * MW];        // 340: erosion slice (halo 1, masked)
    __shared__ float xHW[3][TH * TW];    // 768: max over W,H of e, 3-slice circular
    __shared__ float wsum[4];
    __shared__ int s_active;

    const int t = threadIdx.x;

    // gating: active iff all previous dn >= STOP_THRESH
    if (t == 0) {
        int act = 1;
        for (int j = 1; j < step; ++j) {
            if (!(slots[j] >= STOP_THRESH * (double)NTOT)) { act = 0; break; }
        }
        s_active = act;
    }
    __syncthreads();
    if (!s_active) return;

    const int bx = blockIdx.x, by = blockIdx.y;
    const int bz = blockIdx.z & 3, img = blockIdx.z >> 2;
    const int x0 = bx * TW, y0 = by * TH, z0 = bz * TDZ;

    const float* in = a_in + (size_t)img * NPI;
    float* aout = a_out + (size_t)img * NPI;
    float* sk = skel + (size_t)img * NPI;

    // ---- per-thread precompute (all div/mod hoisted out of the z loop) ----
    // load stage: positions t and t+256 in the 12x36 footprint
    const int l0 = t, l1 = t + 256;
    const bool l1v = (l1 < FH * FW);
    const int fh0 = l0 / FW, fw0 = l0 % FW;
    const int fh1 = l1v ? l1 / FW : 0, fw1 = l1v ? l1 % FW : 0;
    const int gy0 = y0 - 2 + fh0, gx0 = x0 - 2 + fw0;
    const int gy1 = y0 - 2 + fh1, gx1 = x0 - 2 + fw1;
    const bool v0 = ((unsigned)gy0 < H_DIM) & ((unsigned)gx0 < W_DIM);
    const bool v1 = l1v && ((unsigned)gy1 < H_DIM) & ((unsigned)gx1 < W_DIM);
    const int off0 = gy0 * W_DIM + gx0, off1 = gy1 * W_DIM + gx1;

    // minWH stage: positions t and t+256 in the 10x34 grid
    const int m0 = t, m1 = t + 256;
    const bool m1v = (m1 < MH * MW);
    const int mh0 = m0 / MW, mw0 = m0 % MW;
    const int mh1 = m1v ? m1 / MW : 0, mw1 = m1v ? m1 % MW : 0;
    const int ma0 = mh0 * FW + mw0, ma1 = mh1 * FW + mw1;
    const bool e0v = ((unsigned)(y0 - 1 + mh0) < H_DIM) & ((unsigned)(x0 - 1 + mw0) < W_DIM);
    const bool e1v = m1v && ((unsigned)(y0 - 1 + mh1) < H_DIM) & ((unsigned)(x0 - 1 + mw1) < W_DIM);

    // output stage: one (oh,ow) column per thread
    const int oh = t >> 5, ow = t & 31;
    const int xb = oh * MW + ow;                       // max9 base in eT
    const int aCenter = (oh + 2) * FW + (ow + 2);
    const int eCenter = (oh + 1) * MW + (ow + 1);
    size_t cgi = ((size_t)z0 * H_DIM + (y0 + oh)) * W_DIM + (x0 + ow);

    const float* pz = in + (ptrdiff_t)(z0 - 2) * HW;

    float acA = 0.f, acB = 0.f, acC = 0.f, ecA = 0.f, ecB = 0.f;
    float lsum = 0.f;

    for (int i = 0; i < TDZ + 4; ++i) {
        const int zl = z0 - 2 + i;
        const bool zlv = (unsigned)zl < D_DIM;
        const int cur = i % 3;

        // stage 1: load input slice footprint (+inf outside volume)
        {
            float va = INFINITY, vb = INFINITY;
            if (zlv) {
                if (v0) va = pz[off0];
                if (v1) vb = pz[off1];
            }
            aS[l0] = va;
            if (l1v) aS[l1] = vb;
        }
        __syncthreads();

        // stage 2: fused 3x3 min over (W,H) -> mHW[cur]; stash a center
        {
            mHW[cur][m0] = min9(aS, ma0);
            if (m1v) mHW[cur][m1] = min9(aS, ma1);
            acC = aS[aCenter];
        }
        __syncthreads();

        // stage 3: min over D -> erosion slice at z' = zl-1, mask out-of-volume
        const bool zpv = (unsigned)(zl - 1) < D_DIM;
        if (i >= 2 && zpv) {
            float v = fminf(fminf(mHW[0][m0], mHW[1][m0]), mHW[2][m0]);
            eT[m0] = e0v ? v : -INFINITY;
            if (m1v) {
                float v2 = fminf(fminf(mHW[0][m1], mHW[1][m1]), mHW[2][m1]);
                eT[m1] = e1v ? v2 : -INFINITY;
            }
        }
        __syncthreads();

        // stage 4: fused 3x3 max over (W,H) of e -> xHW[cur]; stash e center
        if (i >= 2) {
            if (zpv) {
                xHW[cur][t] = max9(eT, xb);
                ecB = eT[eCenter];
            } else {
                xHW[cur][t] = -INFINITY;
                ecB = -INFINITY;
            }
        }
        __syncthreads();

        // stage 5: max over D -> dilation at z'' = zl-2; elementwise update
        if (i >= 4) {
            float dmax = fmaxf(fmaxf(xHW[0][t], xHW[1][t]), xHW[2][t]);
            float delta = leaky(acA - dmax);
            if (step < NUM_ITER) aout[cgi] = ecA;   // a_out = erosion
            if (step == 0) {
                sk[cgi] = delta;
            } else {
                float g = sk[cgi];
                float upd = leaky(delta - g * delta);
                float gn = g + upd;
                sk[cgi] = gn;
                lsum += (step == 1) ? fabsf(gn) : fabsf(upd);
            }
            cgi += HW;
        }

        acA = acB; acB = acC; ecA = ecB;
        pz += HW;
    }

    // dn reduction: one double atomic per block
    if (step > 0) {
        #pragma unroll
        for (int off = 32; off > 0; off >>= 1)
            lsum += __shfl_down(lsum, off, 64);
        const int lane = t & 63, wid = t >> 6;
        if (lane == 0) wsum[wid] = lsum;
        __syncthreads();
        if (t == 0) {
            float b = wsum[0] + wsum[1] + wsum[2] + wsum[3];
            atomicAdd(&slots[step], (double)b);
        }
    }
}

extern "C" void kernel_launch(void* const* d_in, const int* in_sizes, int n_in,
                              void* d_out, int out_size, void* d_ws, size_t ws_size,
                              hipStream_t stream) {
    const float* img = (const float*)d_in[0];
    float* out = (float*)d_out;
    float* buf0 = (float*)d_ws;
    float* buf1 = buf0 + NTOT;
    double* slots = (double*)(buf1 + NTOT);

    init_slots<<<1, 64, 0, stream>>>(slots);

    dim3 grid(W_DIM / TW, H_DIM / TH, (D_DIM / TDZ) * NIMG);
    for (int s = 0; s <= NUM_ITER; ++s) {
        const float* ain = (s == 0) ? img : ((s & 1) ? buf0 : buf1);
        float* aout = (s & 1) ? buf1 : buf0;
        skel_step<<<grid, 256, 0, stream>>>(ain, aout, out, slots, s);
    }
}

// Round 3
// 449.633 us; speedup vs baseline: 2.2196x; 1.0968x over previous
//
#include <hip/hip_runtime.h>
#include <math.h>

#define D_DIM 128
#define H_DIM 256
#define W_DIM 256
#define HW (H_DIM * W_DIM)
#define NIMG 2
#define NPI (D_DIM * HW)
#define NTOT (NIMG * NPI)

#define TDZ 32
#define TH 8
#define TW 32
#define FH 12      // TH+4 (halo 2)
#define FW 36      // TW+4
#define MH 10      // TH+2 (halo 1)
#define MW 34      // TW+2

#define NUM_ITER 20
#define STOP_THRESH 1e-4

__device__ __forceinline__ float leaky(float x) { return x >= 0.f ? x : 0.01f * x; }

__device__ __forceinline__ float min9(const float* s, int b) {
    float a = fminf(fminf(s[b], s[b + 1]), s[b + 2]);
    float c = fminf(fminf(s[b + FW], s[b + FW + 1]), s[b + FW + 2]);
    float d = fminf(fminf(s[b + 2 * FW], s[b + 2 * FW + 1]), s[b + 2 * FW + 2]);
    return fminf(fminf(a, c), d);
}

__device__ __forceinline__ float max9(const float* s, int b) {
    float a = fmaxf(fmaxf(s[b], s[b + 1]), s[b + 2]);
    float c = fmaxf(fmaxf(s[b + MW], s[b + MW + 1]), s[b + MW + 2]);
    float d = fmaxf(fmaxf(s[b + 2 * MW], s[b + 2 * MW + 1]), s[b + 2 * MW + 2]);
    return fmaxf(fmaxf(a, c), d);
}

__global__ void init_slots(double* slots) {
    if (threadIdx.x < 32) slots[threadIdx.x] = 0.0;
}

// Rolling-slice fused step, register-pipelined:
//   e = minpool3^3(a_in) (erosion, +inf pad), a_out = e,
//   d = maxpool3^3(e)    (-inf pad), delta = leaky(a_in - d),
//   skel update + dn accumulation.
// D-direction reductions live in per-thread rotating registers (same thread
// writes & reads), so only 2 LDS buffers + 2 barriers per slice; global loads
// for slice i+1 are issued before slice i's barrier (one-slice prefetch).
__global__ __launch_bounds__(256) void skel_step(
    const float* __restrict__ a_in,
    float* __restrict__ a_out,
    float* __restrict__ skel,
    double* __restrict__ slots,
    int step)
{
    __shared__ float aS[FH * FW];     // 432 floats: input slice footprint (halo 2)
    __shared__ float eT[MH * MW];     // 340 floats: erosion slice (halo 1, masked)
    __shared__ float wsum[4];
    __shared__ int s_active;

    const int t = threadIdx.x;

    // gating: active iff all previous dn >= STOP_THRESH
    if (t == 0) {
        int act = 1;
        for (int j = 1; j < step; ++j) {
            if (!(slots[j] >= STOP_THRESH * (double)NTOT)) { act = 0; break; }
        }
        s_active = act;
    }
    __syncthreads();
    if (!s_active) return;

    const int bx = blockIdx.x, by = blockIdx.y;
    const int bz = blockIdx.z & 3, img = blockIdx.z >> 2;
    const int x0 = bx * TW, y0 = by * TH, z0 = bz * TDZ;

    const float* in = a_in + (size_t)img * NPI;
    float* aout = a_out + (size_t)img * NPI;
    float* sk = skel + (size_t)img * NPI;

    // ---- per-thread precompute (hoisted out of the z loop) ----
    // load stage: positions t and t+256 in the 12x36 footprint
    const int l0 = t, l1 = t + 256;
    const bool l1v = (l1 < FH * FW);
    const int fh0 = l0 / FW, fw0 = l0 % FW;
    const int fh1 = l1v ? l1 / FW : 0, fw1 = l1v ? l1 % FW : 0;
    const int gy0 = y0 - 2 + fh0, gx0 = x0 - 2 + fw0;
    const int gy1 = y0 - 2 + fh1, gx1 = x0 - 2 + fw1;
    const bool v0 = ((unsigned)gy0 < H_DIM) & ((unsigned)gx0 < W_DIM);
    const bool v1 = l1v && ((unsigned)gy1 < H_DIM) & ((unsigned)gx1 < W_DIM);
    const int off0 = gy0 * W_DIM + gx0, off1 = gy1 * W_DIM + gx1;

    // min/erosion stage: positions t and t+256 in the 10x34 grid
    const int m0 = t, m1 = t + 256;
    const bool m1v = (m1 < MH * MW);
    const int mh0 = m0 / MW, mw0 = m0 % MW;
    const int mh1 = m1v ? m1 / MW : 0, mw1 = m1v ? m1 % MW : 0;
    const int ma0 = mh0 * FW + mw0, ma1 = mh1 * FW + mw1;
    const bool e0v = ((unsigned)(y0 - 1 + mh0) < H_DIM) & ((unsigned)(x0 - 1 + mw0) < W_DIM);
    const bool e1v = m1v && ((unsigned)(y0 - 1 + mh1) < H_DIM) & ((unsigned)(x0 - 1 + mw1) < W_DIM);

    // output stage: one (oh,ow) column per thread
    const int oh = t >> 5, ow = t & 31;
    const int xb = oh * MW + ow;
    const int aCenter = (oh + 2) * FW + (ow + 2);
    const int eCenter = (oh + 1) * MW + (ow + 1);
    size_t cgi = ((size_t)z0 * H_DIM + (y0 + oh)) * W_DIM + (x0 + ow);

    // rotating registers for D-direction reductions
    float m0P2 = 0.f, m0P1 = 0.f, m0C = 0.f;
    float m1P2 = 0.f, m1P1 = 0.f, m1C = 0.f;
    float xP2 = 0.f, xP1 = 0.f, xC = 0.f;
    float acA = 0.f, acB = 0.f, acC = 0.f, ecA = 0.f, ecB = 0.f;
    float lsum = 0.f;

    // prefetch slice i=0 (zl = z0-2)
    float pf0 = INFINITY, pf1 = INFINITY;
    {
        int z = z0 - 2;
        if ((unsigned)z < D_DIM) {
            const float* p = in + (size_t)z * HW;
            if (v0) pf0 = p[off0];
            if (v1) pf1 = p[off1];
        }
    }
    const float* pzn = in + (ptrdiff_t)(z0 - 1) * HW;   // slice for prefetch at iter i

    for (int i = 0; i < TDZ + 4; ++i) {
        const int zl = z0 - 2 + i;

        // stage 1: commit prefetched slice to LDS, then issue next prefetch
        aS[l0] = pf0;
        if (l1v) aS[l1] = pf1;
        pf0 = INFINITY; pf1 = INFINITY;
        {
            const int zn = zl + 1;
            if (i < TDZ + 3 && (unsigned)zn < D_DIM) {
                if (v0) pf0 = pzn[off0];
                if (v1) pf1 = pzn[off1];
            }
        }
        pzn += HW;
        __syncthreads();

        // stage 2: fused 3x3 min over (W,H) into registers; erosion slice to LDS
        m0C = min9(aS, ma0);
        if (m1v) m1C = min9(aS, ma1);
        acC = aS[aCenter];

        const bool zpv = (unsigned)(zl - 1) < D_DIM;   // erosion slice in volume?
        if (i >= 2 && zpv) {
            eT[m0] = e0v ? fminf(fminf(m0P2, m0P1), m0C) : -INFINITY;
            if (m1v) eT[m1] = e1v ? fminf(fminf(m1P2, m1P1), m1C) : -INFINITY;
        }
        __syncthreads();

        // stage 3: fused 3x3 max over (W,H) into register; D-max; outputs
        if (i >= 2) {
            if (zpv) {
                xC = max9(eT, xb);
                ecB = eT[eCenter];
            } else {
                xC = -INFINITY;
                ecB = -INFINITY;
            }
        }
        if (i >= 4) {
            float dmax = fmaxf(fmaxf(xP2, xP1), xC);
            float delta = leaky(acA - dmax);
            if (step < NUM_ITER) aout[cgi] = ecA;
            if (step == 0) {
                sk[cgi] = delta;
            } else {
                float g = sk[cgi];
                float upd = leaky(delta - g * delta);
                float gn = g + upd;
                sk[cgi] = gn;
                lsum += (step == 1) ? fabsf(gn) : fabsf(upd);
            }
            cgi += HW;
        }

        // rotate
        m0P2 = m0P1; m0P1 = m0C;
        m1P2 = m1P1; m1P1 = m1C;
        xP2 = xP1;   xP1 = xC;
        acA = acB;   acB = acC;
        ecA = ecB;
    }

    // dn reduction: one double atomic per block
    if (step > 0) {
        #pragma unroll
        for (int off = 32; off > 0; off >>= 1)
            lsum += __shfl_down(lsum, off, 64);
        const int lane = t & 63, wid = t >> 6;
        if (lane == 0) wsum[wid] = lsum;
        __syncthreads();
        if (t == 0) {
            float b = wsum[0] + wsum[1] + wsum[2] + wsum[3];
            atomicAdd(&slots[step], (double)b);
        }
    }
}

extern "C" void kernel_launch(void* const* d_in, const int* in_sizes, int n_in,
                              void* d_out, int out_size, void* d_ws, size_t ws_size,
                              hipStream_t stream) {
    const float* img = (const float*)d_in[0];
    float* out = (float*)d_out;
    float* buf0 = (float*)d_ws;
    float* buf1 = buf0 + NTOT;
    double* slots = (double*)(buf1 + NTOT);

    init_slots<<<1, 64, 0, stream>>>(slots);

    dim3 grid(W_DIM / TW, H_DIM / TH, (D_DIM / TDZ) * NIMG);
    for (int s = 0; s <= NUM_ITER; ++s) {
        const float* ain = (s == 0) ? img : ((s & 1) ? buf0 : buf1);
        float* aout = (s & 1) ? buf1 : buf0;
        skel_step<<<grid, 256, 0, stream>>>(ain, aout, out, slots, s);
    }
}